// Round 12
// baseline (135.590 us; speedup 1.0000x reference)
//
#include <hip/hip_runtime.h>
#include <stdint.h>
#include <math.h>

#define TPB   512    // 8 waves/block
#define KTOP  100
#define K1    128    // selection rank cut (per-slice in s1, per-image in s2)
#define KSLOT 256    // per-slice emitted u32 slots (K1 + fat tie-bin margin)
#define CAP   1536   // stage-1 survivor capacity (~855 expected/slice, +24 sigma)
#define SR    16     // slice rows

#define HB 272
#define WB 480
#define NSB 17       // 272/16
#define HP 68
#define WP 120
#define NSP 5        // ceil(68/16), last slice 4 rows
#define NB 64

// ============================================================================
// Validated invariants (prior session + this session, absmax 0.0):
//  - np-f32 softmax p is a MONOTONE function G of D = fl32(x1-x0);
//    G collapse window: for mx>0, ~6e-8*e^mx; for mx<=0, bounded by ~1e-6.
//  - NMS: keep iff p >= all 8 neighbors; D-space fast path + exact G on ties.
//  - top-k tie order: (p desc, idx asc)  ==  u64 key (p_bits<<32 | ~idx) desc.
//  - per-slice D16 rank-128 cut contains the slice's exact top-100.
//  - wave-0 in-register scan+pick (R10 wave_pick) == LDS suffix_scan + pick.
// Ladder: R8 139.4 -> R14 128.1 (scaled tie certificate: distinct if
//  mx-v >= 4e-6*e^max(mx,0)) -> R15 126.3 (col-max, direct emit, batched
//  stage2 load) -> R16 125.9 (SR=16, neutral: per-block path scales w/ tile).
// R17: phase-chain shortening, no restructure:
//  - scan_pick_256: wave-0 in-register suffix-scan + crossing pick; replaces
//    {scan + writeback + barrier + 256-thread pick + barrier} (x2 per kernel).
//  - stage2 keys stay in REGISTERS (kr[u] from the batched load); hist2 and
//    compact passes run from regs; LDS keys array + its 3 passes deleted.
// ============================================================================
__device__ __forceinline__ float G_exact(float D) {
    float t = -fabsf(D);
    float etf = (float)exp((double)t);       // correctly-rounded f32 exp
    return (D > 0.0f) ? __fdiv_rn(1.0f, __fadd_rn(etf, 1.0f))
                      : __fdiv_rn(etf, __fadd_rn(1.0f, etf));
}

__device__ __forceinline__ uint32_t flip_f32(float D) {
    uint32_t u = __float_as_uint(D);
    return (u & 0x80000000u) ? ~u : (u | 0x80000000u);
}

// Wave-aggregated counter push (stage2 compact: low-frequency call sites).
__device__ __forceinline__ int agg_push(int* ctr, bool active) {
    uint64_t m = __ballot(active);
    int pos = -1;
    if (active) {
        int lane = threadIdx.x & 63;
        int lead = __ffsll((unsigned long long)m) - 1;
        int before = (int)__popcll(m & ((1ull << lane) - 1ull));
        int base = 0;
        if (lane == lead) base = atomicAdd(ctr, (int)__popcll(m));
        base = __shfl(base, lead, 64);
        pos = base + before;
    }
    return pos;
}

// Clustered histogram add: one atomicAdd per DISTINCT bin per wave.
__device__ __forceinline__ void hist_clustered(uint32_t* hist, uint32_t bin, bool active) {
    uint64_t todo = __ballot(active);
    while (todo) {
        int lead = __ffsll((unsigned long long)todo) - 1;
        uint32_t b = (uint32_t)__shfl((int)bin, lead, 64);
        uint64_t same = __ballot(active && (bin == b));
        if ((int)(threadIdx.x & 63) == lead) atomicAdd(&hist[b], (uint32_t)__popcll(same));
        todo &= ~same;
    }
}

// Wave-0 in-register suffix-scan + crossing pick over a 256-bin LDS hist.
// Writes: *s_bin = bin i with suffix(i) >= kk > suffix(i+1), *s_ab =
// suffix(i+1); *s_none = 1 if total < kk. Exactly one lane matches (suffix
// non-increasing). One barrier. (logic == R10 wave_pick, validated)
__device__ __forceinline__ void scan_pick_256(const uint32_t* hist, uint32_t kk,
                                              uint32_t* s_bin, uint32_t* s_ab,
                                              uint32_t* s_none)
{
    if (threadIdx.x < 64) {
        int lane = threadIdx.x;
        uint32_t h0 = hist[4*lane+0], h1 = hist[4*lane+1];
        uint32_t h2 = hist[4*lane+2], h3 = hist[4*lane+3];
        uint32_t tot = h0 + h1 + h2 + h3;
        uint32_t run = tot;
        #pragma unroll
        for (int d = 1; d < 64; d <<= 1) {
            uint32_t o = __shfl_down(run, d, 64);
            if (lane + d < 64) run += o;
        }
        uint32_t ab = run - tot;                  // suffix strictly above lane's bins
        uint32_t S3 = ab + h3, S2 = S3 + h2, S1 = S2 + h1, S0 = S1 + h0; // S0==run
        uint32_t Sn = __shfl_down(S0, 1, 64);     // suffix at bin 4(lane+1)
        if (lane == 63) Sn = 0;
        uint32_t total = (uint32_t)__shfl((int)run, 0, 64);
        if (lane == 0 && total < kk) *s_none = 1;
        int fb = -1; uint32_t fs = 0;
        if (S0 >= kk && S1 < kk) { fb = 4*lane+0; fs = S1; }
        if (S1 >= kk && S2 < kk) { fb = 4*lane+1; fs = S2; }
        if (S2 >= kk && S3 < kk) { fb = 4*lane+2; fs = S3; }
        if (S3 >= kk && Sn < kk) { fb = 4*lane+3; fs = Sn; }
        if (fb >= 0) { *s_bin = (uint32_t)fb; *s_ab = fs; }
    }
    __syncthreads();
}

// 6-wide row window [c4-1 .. c4+4] from the LDS D-tile (OOB -> -inf).
template<int W>
__device__ __forceinline__ void row6(const float* df, int row, int c4, float* a) {
    const float4 m = ((const float4*)df)[(row * W + c4) >> 2];
    a[1] = m.x; a[2] = m.y; a[3] = m.z; a[4] = m.w;
    a[0] = (c4 > 0)     ? df[row * W + c4 - 1] : -INFINITY;
    a[5] = (c4 + 4 < W) ? df[row * W + c4 + 4] : -INFINITY;
}

// ---- stage 1 body: NMS + D16 radix-select, emit u32 slots ------------------
template<int H, int W, int NS>
__device__ __forceinline__ void stage1_impl(const float* __restrict__ x,
                                            int s, int b,
                                            uint32_t* __restrict__ key_out,
                                            unsigned char* smem)
{
    constexpr int W4 = W / 4;
    constexpr int tileRows = SR + 2;
    const int r0 = s * SR;
    const int rows = (H - r0 < SR) ? (H - r0) : SR;

    float*    df    = (float*)smem;                        // tileRows * W
    uint32_t* surv  = (uint32_t*)(df + tileRows * W);      // CAP
    uint32_t* hist  = surv + CAP;                          // 256
    uint32_t* hist2 = hist + 256;                          // 256 (level-2)
    __shared__ int s_cnt, s_out;
    __shared__ uint32_t s_bin, s_ab, s_bin2, s_ab2, s_none;
    if (threadIdx.x == 0) { s_cnt = 0; s_out = 0; s_none = 0; }
    if (threadIdx.x < 256) { hist[threadIdx.x] = 0; hist2[threadIdx.x] = 0; }

    // Direct-global emit: zero this slice's KSLOT slots now (overlaps tile
    // load); the compact scatter overwrites [0, s_out) later.
    uint32_t* ko = key_out + ((size_t)b * NS + s) * KSLOT;
    if (threadIdx.x < KSLOT) ko[threadIdx.x] = 0u;

    const float*  x0  = x + (size_t)b * 2 * H * W;
    const float*  x1  = x0 + (size_t)H * W;
    const float4* x0v = (const float4*)x0;
    const float4* x1v = (const float4*)x1;
    float4* dfv = (float4*)df;

    // D tile (rows r0-1 .. r0+SR), float4-vectorized; OOB rows -> -inf.
    constexpr int nt4 = tileRows * W4;
    for (int t = threadIdx.x; t < nt4; t += TPB) {
        int tr = t / W4, c4 = t - tr * W4;        // compile-time divisor
        int r = r0 - 1 + tr;
        float4 d4 = make_float4(-INFINITY, -INFINITY, -INFINITY, -INFINITY);
        if (r >= 0 && r < H) {
            float4 a = x0v[r * W4 + c4];
            float4 c = x1v[r * W4 + c4];
            d4.x = __fsub_rn(c.x, a.x);
            d4.y = __fsub_rn(c.y, a.y);
            d4.z = __fsub_rn(c.z, a.z);
            d4.w = __fsub_rn(c.w, a.w);
        }
        dfv[t] = d4;
    }
    __syncthreads();

    // NMS (4 cells/iter) + level-1 histogram fused into the keep path.
    // Column-max sharing (bit-identical 8-neighbor max); R14 scaled tie
    // certificate -> f64 G_exact fires ~30x per RUN.
    const int groups = rows * W4;
    for (int g = threadIdx.x; g < groups; g += TPB) {
        int lr = g / W4, c4 = (g - lr * W4) << 2; // compile-time divisor
        int tr = lr + 1;
        float ap[6], ac[6], an[6], vx[6];
        row6<W>(df, tr - 1, c4, ap);
        row6<W>(df, tr,     c4, ac);
        row6<W>(df, tr + 1, c4, an);
        #pragma unroll
        for (int i = 0; i < 6; ++i) vx[i] = fmaxf(fmaxf(ap[i], an[i]), ac[i]);
        #pragma unroll
        for (int j = 0; j < 4; ++j) {
            float v = ac[j + 1];
            float mx = fmaxf(fmaxf(fmaxf(vx[j], vx[j+2]), ap[j+1]), an[j+1]);
            float thr = 4e-6f * __expf(fmaxf(mx, 0.0f)); // >=16x/4x margin certificate
            bool keep;
            if (v >= mx) keep = true;                    // exact
            else if (mx - v >= thr) keep = false;        // certified G-distinct
            else keep = (G_exact(v) == G_exact(mx));     // ultra-rare exact tie check
            if (keep) {
                uint32_t key16 = flip_f32(v) >> 16;
                int pos = atomicAdd(&s_cnt, 1);
                if (pos < CAP)
                    surv[pos] = (key16 << 16) | ((uint32_t)lr << 9) | (uint32_t)(c4 + j);
                atomicAdd(&hist[key16 >> 8], 1u);
            }
        }
    }
    __syncthreads();
    const int n = (s_cnt < CAP) ? s_cnt : CAP;

    // Level-1 select on D16 high byte (in-register scan+pick, 1 barrier).
    scan_pick_256(hist, K1, &s_bin, &s_ab, &s_none);

    uint32_t T16 = 0;
    if (!s_none) {
        const uint32_t b3 = s_bin;
        const uint32_t k2 = K1 - s_ab;
        // Level-2: hist2 pre-zeroed in the init phase (no rezero barrier).
        for (int t = threadIdx.x; t < n; t += TPB) {
            uint32_t sv = surv[t];
            if ((sv >> 24) == b3) atomicAdd(&hist2[(sv >> 16) & 255u], 1u);
        }
        __syncthreads();
        // Level-2 crossing always exists (bin count >= k2 by construction).
        scan_pick_256(hist2, k2, &s_bin2, &s_ab2, &s_none);
        T16 = (b3 << 8) | s_bin2;
    }

    // Compact survivors with D16 >= T16: scatter directly to global.
    for (int t = threadIdx.x; t < n; t += TPB) {
        uint32_t sv = surv[t];
        if ((sv >> 16) >= T16) {
            int pos = atomicAdd(&s_out, 1);
            if (pos < KSLOT) ko[pos] = sv;
        }
    }
}

__global__ __launch_bounds__(TPB) void stage1(const float* __restrict__ bmap,
                                              const float* __restrict__ pmap,
                                              uint32_t* __restrict__ bkey,
                                              uint32_t* __restrict__ pkey)
{
    extern __shared__ unsigned char smem[];
    if (blockIdx.x < NSB)
        stage1_impl<HB, WB, NSB>(bmap, blockIdx.x, blockIdx.y, bkey, smem);
    else
        stage1_impl<HP, WP, NSP>(pmap, blockIdx.x - NSB, blockIdx.y, pkey, smem);
}

// ---- stage 2 body: D16 select -> exact-p re-rank of <=256 -> decode --------
// Keys live in REGISTERS (kr[u]); hist1/hist2/compact all run from regs.
template<int H, int W, int NS, bool BALL>
__device__ __forceinline__ void stage2_impl(const float* __restrict__ xmap,
                                            const float* __restrict__ pbbox,
                                            const uint32_t* __restrict__ key_in,
                                            float* __restrict__ outp,
                                            int b, unsigned char* smem)
{
    constexpr int M = NS * KSLOT;
    constexpr int NLD = (M + TPB - 1) / TPB;
    const float* x0 = xmap + (size_t)b * 2 * H * W;
    const float* x1 = x0 + (size_t)H * W;
    const uint32_t* kin = key_in + (size_t)b * M;

    uint32_t* hist  = (uint32_t*)smem;           // 256 (level-1)
    uint32_t* hist2 = hist + 256;                // 256 (level-2)
    uint32_t* rnk   = hist2 + 256;               // 256 (ranks)
    uint64_t* outb  = (uint64_t*)(rnk + 256);    // 256
    __shared__ int s_out;
    __shared__ uint32_t s_bin, s_ab, s_bin2, s_ab2, s_none;
    if (threadIdx.x == 0) { s_out = 0; s_none = 0; }
    if (threadIdx.x < 256) {
        hist[threadIdx.x] = 0; hist2[threadIdx.x] = 0;
        rnk[threadIdx.x] = 0; outb[threadIdx.x] = 0;
    }
    // Defensive zero of the 100 output rows (rank-scatter fills real rows).
    for (int t = threadIdx.x; t < KTOP * 5; t += TPB) outp[t] = 0.f;
    __syncthreads();

    // Batched key load into registers (sched_barrier(0) pins issue -- at
    // 1 blk/CU nothing else hides the round-trips), then level-1 histogram.
    uint32_t kr[NLD];
    #pragma unroll
    for (int u = 0; u < NLD; ++u) {
        int t = threadIdx.x + u * TPB;
        kr[u] = (t < M) ? kin[t] : 0u;
    }
    __builtin_amdgcn_sched_barrier(0);
    #pragma unroll
    for (int u = 0; u < NLD; ++u) {
        int t = threadIdx.x + u * TPB;
        hist_clustered(hist, kr[u] >> 24, (t < M) && (kr[u] != 0u));
    }
    __syncthreads();

    // Level-1 select (in-register scan+pick, 1 barrier).
    scan_pick_256(hist, K1, &s_bin, &s_ab, &s_none);

    uint32_t T16 = 0;
    if (!s_none) {
        const uint32_t b3 = s_bin;
        const uint32_t k2 = K1 - s_ab;
        // Level-2 histogram from registers.
        #pragma unroll
        for (int u = 0; u < NLD; ++u) {
            uint32_t k = kr[u];
            if (k && (k >> 24) == b3) atomicAdd(&hist2[(k >> 16) & 255u], 1u);
        }
        __syncthreads();
        scan_pick_256(hist2, k2, &s_bin2, &s_ab2, &s_none);
        T16 = (b3 << 8) | s_bin2;
    }

    // Compact finalists from registers into pre-zeroed outb; exact np p
    // computed only here (D re-gathered from the map).
    #pragma unroll
    for (int u = 0; u < NLD; ++u) {
        int t = threadIdx.x + u * TPB;
        uint32_t k = kr[u];
        bool take = (t < M) && (k != 0) && ((k >> 16) >= T16);
        int pos = agg_push(&s_out, take);
        if (take && pos < 256) {
            int sIdx = t / KSLOT;                      // KSLOT=256 -> shift
            int lr = (k >> 9) & 15, c = k & 511;       // lr: 4 bits (SR=16)
            int gidx = (sIdx * SR + lr) * W + c;
            float D = __fsub_rn(x1[gidx], x0[gidx]);
            float p = G_exact(D);
            outb[pos] = ((uint64_t)__float_as_uint(p) << 32) | (uint32_t)(~gidx);
        }
    }
    __syncthreads();

    // Rank-by-counting over unique u64 keys (2 barriers vs bitonic's 36).
    {
        int i = threadIdx.x & 255;
        int half = threadIdx.x >> 8;
        uint64_t ki = outb[i];
        uint32_t cnt = 0;
        int j0 = half * 128;
        #pragma unroll 4
        for (int j = j0; j < j0 + 128; ++j) cnt += (outb[j] > ki) ? 1u : 0u;
        atomicAdd(&rnk[i], cnt);
    }
    __syncthreads();

    // Decode: finalist with rank r < KTOP writes output row r directly.
    if (threadIdx.x < 256) {
        uint64_t k = outb[threadIdx.x];
        uint32_t r = rnk[threadIdx.x];
        if (k != 0 && r < KTOP) {
            int id = (int)(~(uint32_t)k);
            float val = __uint_as_float((uint32_t)(k >> 32));
            int yy = id / W, xx = id - yy * W;             // compile-time divisor
            constexpr float ds = BALL ? 4.0f : 16.0f;
            float xc = (float)xx * ds + (ds - 1.0f) * 0.5f;
            float yc = (float)yy * ds + (ds - 1.0f) * 0.5f;
            float t0 = 0.f, t1 = 0.f;
            float t2 = BALL ? 40.0f : 0.0f, t3 = BALL ? 40.0f : 0.0f;
            if (!BALL) {
                const float* bb = pbbox + (size_t)b * 4 * H * W;
                constexpr float sx = (float)W * ds, sy = (float)H * ds;
                t0 = bb[id]             * sx;
                t1 = bb[id + H * W]     * sy;
                t2 = bb[id + 2 * H * W] * sx;
                t3 = bb[id + 3 * H * W] * sy;
            }
            float bx = xc + t0, by = yc + t1;
            float* op = outp + (size_t)r * 5;
            op[0] = bx - 0.5f * t2;
            op[1] = by - 0.5f * t3;
            op[2] = bx + 0.5f * t2;
            op[3] = by + 0.5f * t3;
            op[4] = val;
        }
    }
}

__global__ __launch_bounds__(TPB) void stage2(const float* __restrict__ bmap,
                                              const float* __restrict__ pmap,
                                              const float* __restrict__ pbbox,
                                              const uint32_t* __restrict__ bkey,
                                              const uint32_t* __restrict__ pkey,
                                              float* __restrict__ out)
{
    extern __shared__ unsigned char smem[];
    if (blockIdx.x < NB) {
        int b = blockIdx.x;
        stage2_impl<HB, WB, NSB, true>(bmap, nullptr, bkey,
            out + (size_t)NB * KTOP * 5 + (size_t)b * KTOP * 5, b, smem);
    } else {
        int b = blockIdx.x - NB;
        stage2_impl<HP, WP, NSP, false>(pmap, pbbox, pkey,
            out + (size_t)b * KTOP * 5, b, smem);
    }
}

// ---- launch -----------------------------------------------------------------
extern "C" void kernel_launch(void* const* d_in, const int* in_sizes, int n_in,
                              void* d_out, int out_size, void* d_ws, size_t ws_size,
                              hipStream_t stream) {
    const float* pmap  = (const float*)d_in[0];   // [64,2,68,120]
    const float* pbbox = (const float*)d_in[1];   // [64,4,68,120]
    const float* bmap  = (const float*)d_in[2];   // [64,2,272,480]
    float* out = (float*)d_out;                   // player [64,100,5] then ball

    uint32_t* ws_bkey = (uint32_t*)d_ws;                       // 64*17*256 u32
    uint32_t* ws_pkey = ws_bkey + (size_t)NB * NSB * KSLOT;    // 64*5*256 u32
    // total ws: 1,441,792 B (within proven budget)

    // LDS: df 18*480*4=34560 + surv 6144 + hist 1024 + hist2 1024 = 42752 B
    size_t lds1 = (size_t)(SR + 2) * WB * 4 + (size_t)CAP * 4 + 2048;
    stage1<<<dim3(NSB + NSP, NB), TPB, lds1, stream>>>(bmap, pmap, ws_bkey, ws_pkey);

    // LDS: hist 1024 + hist2 1024 + rnk 1024 + outb 2048 = 5120 B
    size_t lds2 = 5120;
    stage2<<<2 * NB, TPB, lds2, stream>>>(bmap, pmap, pbbox, ws_bkey, ws_pkey, out);
}

// Round 13
// 124.966 us; speedup vs baseline: 1.0850x; 1.0850x over previous
//
#include <hip/hip_runtime.h>
#include <stdint.h>
#include <math.h>

#define TPB   512    // 8 waves/block
#define KTOP  100
#define K1    128    // selection rank cut (per-slice in s1, per-image in s2)
#define KSLOT 256    // per-slice emitted u32 slots (K1 + fat tie-bin margin)
#define CAP   1536   // stage-1 survivor capacity (~855 expected/slice, +24 sigma)
#define SR    16     // slice rows

#define HB 272
#define WB 480
#define NSB 17       // 272/16
#define HP 68
#define WP 120
#define NSP 5        // ceil(68/16), last slice 4 rows
#define NB 64

// ============================================================================
// Validated invariants (prior session + this session, absmax 0.0):
//  - np-f32 softmax p is a MONOTONE function G of D = fl32(x1-x0);
//    G collapse window: for mx>0, ~6e-8*e^mx; for mx<=0, bounded by ~1e-6.
//  - NMS: keep iff p >= all 8 neighbors; D-space fast path + exact G on ties.
//  - top-k tie order: (p desc, idx asc)  ==  u64 key (p_bits<<32 | ~idx) desc.
//  - per-slice D16 rank-128 cut contains the slice's exact top-100.
// Ladder: R8 139.4 -> R14 128.1 (scaled tie certificate: distinct if
//  mx-v >= 4e-6*e^max(mx,0); f64 G_exact ~30 calls/run) -> R15 126.3
//  (col-max sharing, direct-global emit, stage2 batched key load) ->
//  R16 125.9 (SR=16; best measured).
// R18 = R16 VERBATIM. R17 (wave-0 scan_pick + reg-resident stage2 keys)
//  regressed to 135.6: stage1 41.3us measured, VALUBusy 20% -- the serial
//  wave-0 scan+pick chain (2x per block, 7 waves parked) replaced a wide
//  256-thread pick that previously hid under the barrier. Reverted.
// Structural hypotheses measured & rejected for stage1: VALU-defer queue
//  (R6), wave-aggregated atomics (R7), persistent blocks (R9), 1-wave
//  autonomous (R10), TPB=256 (R13), SR=16-rounds (R16 neutral), serial
//  scan_pick (R17). Remaining stage1 time is latency-structural.
// ============================================================================
__device__ __forceinline__ float G_exact(float D) {
    float t = -fabsf(D);
    float etf = (float)exp((double)t);       // correctly-rounded f32 exp
    return (D > 0.0f) ? __fdiv_rn(1.0f, __fadd_rn(etf, 1.0f))
                      : __fdiv_rn(etf, __fadd_rn(1.0f, etf));
}

__device__ __forceinline__ uint32_t flip_f32(float D) {
    uint32_t u = __float_as_uint(D);
    return (u & 0x80000000u) ? ~u : (u | 0x80000000u);
}

// Wave-aggregated counter push (stage2 only: low-frequency call sites).
__device__ __forceinline__ int agg_push(int* ctr, bool active) {
    uint64_t m = __ballot(active);
    int pos = -1;
    if (active) {
        int lane = threadIdx.x & 63;
        int lead = __ffsll((unsigned long long)m) - 1;
        int before = (int)__popcll(m & ((1ull << lane) - 1ull));
        int base = 0;
        if (lane == lead) base = atomicAdd(ctr, (int)__popcll(m));
        base = __shfl(base, lead, 64);
        pos = base + before;
    }
    return pos;
}

// Clustered histogram add (stage2 load pass only): one atomicAdd per
// DISTINCT bin per wave.
__device__ __forceinline__ void hist_clustered(uint32_t* hist, uint32_t bin, bool active) {
    uint64_t todo = __ballot(active);
    while (todo) {
        int lead = __ffsll((unsigned long long)todo) - 1;
        uint32_t b = (uint32_t)__shfl((int)bin, lead, 64);
        uint64_t same = __ballot(active && (bin == b));
        if ((int)(threadIdx.x & 63) == lead) atomicAdd(&hist[b], (uint32_t)__popcll(same));
        todo &= ~same;
    }
}

// In-place suffix-sum of 256 u32 bins: hist[i] <- sum_{j>=i} hist[j].
// Wave 0 via shuffles; ends with a barrier. (validated)
__device__ __forceinline__ void suffix_scan_256(uint32_t* hist) {
    if (threadIdx.x < 64) {
        int lane = threadIdx.x;
        uint32_t h0 = hist[4*lane+0], h1 = hist[4*lane+1];
        uint32_t h2 = hist[4*lane+2], h3 = hist[4*lane+3];
        uint32_t tot = h0 + h1 + h2 + h3;
        uint32_t run = tot;
        #pragma unroll
        for (int d = 1; d < 64; d <<= 1) {
            uint32_t o = __shfl_down(run, d, 64);
            if (lane + d < 64) run += o;
        }
        uint32_t ab = run - tot;
        hist[4*lane+3] = ab + h3;
        hist[4*lane+2] = ab + h3 + h2;
        hist[4*lane+1] = ab + h3 + h2 + h1;
        hist[4*lane+0] = ab + tot;
    }
    __syncthreads();
}

// 6-wide row window [c4-1 .. c4+4] from the LDS D-tile (OOB -> -inf).
template<int W>
__device__ __forceinline__ void row6(const float* df, int row, int c4, float* a) {
    const float4 m = ((const float4*)df)[(row * W + c4) >> 2];
    a[1] = m.x; a[2] = m.y; a[3] = m.z; a[4] = m.w;
    a[0] = (c4 > 0)     ? df[row * W + c4 - 1] : -INFINITY;
    a[5] = (c4 + 4 < W) ? df[row * W + c4 + 4] : -INFINITY;
}

// ---- stage 1 body: NMS + D16 radix-select, emit u32 slots ------------------
template<int H, int W, int NS>
__device__ __forceinline__ void stage1_impl(const float* __restrict__ x,
                                            int s, int b,
                                            uint32_t* __restrict__ key_out,
                                            unsigned char* smem)
{
    constexpr int W4 = W / 4;
    constexpr int tileRows = SR + 2;
    const int r0 = s * SR;
    const int rows = (H - r0 < SR) ? (H - r0) : SR;

    float*    df    = (float*)smem;                        // tileRows * W
    uint32_t* surv  = (uint32_t*)(df + tileRows * W);      // CAP
    uint32_t* hist  = surv + CAP;                          // 256
    uint32_t* hist2 = hist + 256;                          // 256 (level-2)
    __shared__ int s_cnt, s_out;
    __shared__ uint32_t s_bin, s_ab, s_bin2, s_none;
    if (threadIdx.x == 0) { s_cnt = 0; s_out = 0; s_none = 0; }
    if (threadIdx.x < 256) { hist[threadIdx.x] = 0; hist2[threadIdx.x] = 0; }

    // Direct-global emit: zero this slice's KSLOT slots now (overlaps tile
    // load); the compact scatter overwrites [0, s_out) later.
    uint32_t* ko = key_out + ((size_t)b * NS + s) * KSLOT;
    if (threadIdx.x < KSLOT) ko[threadIdx.x] = 0u;

    const float*  x0  = x + (size_t)b * 2 * H * W;
    const float*  x1  = x0 + (size_t)H * W;
    const float4* x0v = (const float4*)x0;
    const float4* x1v = (const float4*)x1;
    float4* dfv = (float4*)df;

    // D tile (rows r0-1 .. r0+SR), float4-vectorized; OOB rows -> -inf.
    constexpr int nt4 = tileRows * W4;
    for (int t = threadIdx.x; t < nt4; t += TPB) {
        int tr = t / W4, c4 = t - tr * W4;        // compile-time divisor
        int r = r0 - 1 + tr;
        float4 d4 = make_float4(-INFINITY, -INFINITY, -INFINITY, -INFINITY);
        if (r >= 0 && r < H) {
            float4 a = x0v[r * W4 + c4];
            float4 c = x1v[r * W4 + c4];
            d4.x = __fsub_rn(c.x, a.x);
            d4.y = __fsub_rn(c.y, a.y);
            d4.z = __fsub_rn(c.z, a.z);
            d4.w = __fsub_rn(c.w, a.w);
        }
        dfv[t] = d4;
    }
    __syncthreads();

    // NMS (4 cells/iter) + level-1 histogram fused into the keep path.
    // Column-max sharing (bit-identical 8-neighbor max); R14 scaled tie
    // certificate -> f64 G_exact fires ~30x per RUN.
    const int groups = rows * W4;
    for (int g = threadIdx.x; g < groups; g += TPB) {
        int lr = g / W4, c4 = (g - lr * W4) << 2; // compile-time divisor
        int tr = lr + 1;
        float ap[6], ac[6], an[6], vx[6];
        row6<W>(df, tr - 1, c4, ap);
        row6<W>(df, tr,     c4, ac);
        row6<W>(df, tr + 1, c4, an);
        #pragma unroll
        for (int i = 0; i < 6; ++i) vx[i] = fmaxf(fmaxf(ap[i], an[i]), ac[i]);
        #pragma unroll
        for (int j = 0; j < 4; ++j) {
            float v = ac[j + 1];
            float mx = fmaxf(fmaxf(fmaxf(vx[j], vx[j+2]), ap[j+1]), an[j+1]);
            float thr = 4e-6f * __expf(fmaxf(mx, 0.0f)); // >=16x/4x margin certificate
            bool keep;
            if (v >= mx) keep = true;                    // exact
            else if (mx - v >= thr) keep = false;        // certified G-distinct
            else keep = (G_exact(v) == G_exact(mx));     // ultra-rare exact tie check
            if (keep) {
                uint32_t key16 = flip_f32(v) >> 16;
                int pos = atomicAdd(&s_cnt, 1);
                if (pos < CAP)
                    surv[pos] = (key16 << 16) | ((uint32_t)lr << 9) | (uint32_t)(c4 + j);
                atomicAdd(&hist[key16 >> 8], 1u);
            }
        }
    }
    __syncthreads();
    const int n = (s_cnt < CAP) ? s_cnt : CAP;

    // Level-1 select on D16 high byte.
    suffix_scan_256(hist);
    if (threadIdx.x < 256) {
        uint32_t si = hist[threadIdx.x];
        uint32_t sn = (threadIdx.x < 255) ? hist[threadIdx.x + 1] : 0u;
        if (threadIdx.x == 0 && si < K1) s_none = 1;
        if (si >= K1 && sn < K1) { s_bin = threadIdx.x; s_ab = sn; }
    }
    __syncthreads();

    uint32_t T16 = 0;
    if (!s_none) {
        const uint32_t b3 = s_bin;
        const uint32_t k2 = K1 - s_ab;
        // Level-2: hist2 pre-zeroed in the init phase (no rezero barrier).
        for (int t = threadIdx.x; t < n; t += TPB) {
            uint32_t sv = surv[t];
            if ((sv >> 24) == b3) atomicAdd(&hist2[(sv >> 16) & 255u], 1u);
        }
        __syncthreads();
        suffix_scan_256(hist2);
        if (threadIdx.x < 256) {
            uint32_t si = hist2[threadIdx.x];
            uint32_t sn = (threadIdx.x < 255) ? hist2[threadIdx.x + 1] : 0u;
            if (si >= k2 && sn < k2) s_bin2 = threadIdx.x;
        }
        __syncthreads();
        T16 = (b3 << 8) | s_bin2;
    }

    // Compact survivors with D16 >= T16: scatter directly to global.
    for (int t = threadIdx.x; t < n; t += TPB) {
        uint32_t sv = surv[t];
        if ((sv >> 16) >= T16) {
            int pos = atomicAdd(&s_out, 1);
            if (pos < KSLOT) ko[pos] = sv;
        }
    }
}

__global__ __launch_bounds__(TPB) void stage1(const float* __restrict__ bmap,
                                              const float* __restrict__ pmap,
                                              uint32_t* __restrict__ bkey,
                                              uint32_t* __restrict__ pkey)
{
    extern __shared__ unsigned char smem[];
    if (blockIdx.x < NSB)
        stage1_impl<HB, WB, NSB>(bmap, blockIdx.x, blockIdx.y, bkey, smem);
    else
        stage1_impl<HP, WP, NSP>(pmap, blockIdx.x - NSB, blockIdx.y, pkey, smem);
}

// ---- stage 2 body: D16 select -> exact-p re-rank of <=256 -> decode --------
template<int H, int W, int NS, bool BALL>
__device__ __forceinline__ void stage2_impl(const float* __restrict__ xmap,
                                            const float* __restrict__ pbbox,
                                            const uint32_t* __restrict__ key_in,
                                            float* __restrict__ outp,
                                            int b, unsigned char* smem)
{
    constexpr int M = NS * KSLOT;
    const float* x0 = xmap + (size_t)b * 2 * H * W;
    const float* x1 = x0 + (size_t)H * W;
    const uint32_t* kin = key_in + (size_t)b * M;

    uint32_t* keys  = (uint32_t*)smem;           // M
    uint32_t* hist  = keys + M;                  // 256 (level-1)
    uint32_t* hist2 = hist + 256;                // 256 (level-2)
    uint32_t* rnk   = hist2 + 256;               // 256 (ranks)
    uint64_t* outb  = (uint64_t*)(rnk + 256);    // 256
    __shared__ int s_out;
    __shared__ uint32_t s_bin, s_ab, s_bin2, s_none;
    if (threadIdx.x == 0) { s_out = 0; s_none = 0; }
    if (threadIdx.x < 256) {
        hist[threadIdx.x] = 0; hist2[threadIdx.x] = 0;
        rnk[threadIdx.x] = 0; outb[threadIdx.x] = 0;
    }
    // Defensive zero of the 100 output rows (rank-scatter fills real rows).
    for (int t = threadIdx.x; t < KTOP * 5; t += TPB) outp[t] = 0.f;
    __syncthreads();

    // Batched key load: issue ALL global loads into registers before any use
    // (sched_barrier(0) pins issue order -- 1 blk/CU has nothing else to
    // hide the serialized round-trips behind). Then LDS store + hist.
    {
        constexpr int NLD = (M + TPB - 1) / TPB;
        uint32_t kr[NLD];
        #pragma unroll
        for (int u = 0; u < NLD; ++u) {
            int t = threadIdx.x + u * TPB;
            kr[u] = (t < M) ? kin[t] : 0u;
        }
        __builtin_amdgcn_sched_barrier(0);
        #pragma unroll
        for (int u = 0; u < NLD; ++u) {
            int t = threadIdx.x + u * TPB;
            if (t < M) keys[t] = kr[u];
            hist_clustered(hist, kr[u] >> 24, (t < M) && (kr[u] != 0u));
        }
    }
    __syncthreads();
    suffix_scan_256(hist);
    if (threadIdx.x < 256) {
        uint32_t si = hist[threadIdx.x];
        uint32_t sn = (threadIdx.x < 255) ? hist[threadIdx.x + 1] : 0u;
        if (threadIdx.x == 0 && si < K1) s_none = 1;
        if (si >= K1 && sn < K1) { s_bin = threadIdx.x; s_ab = sn; }
    }
    __syncthreads();

    uint32_t T16 = 0;
    if (!s_none) {
        const uint32_t b3 = s_bin;
        const uint32_t k2 = K1 - s_ab;
        // Level-2: hist2 pre-zeroed in the init phase.
        for (int t = threadIdx.x; t < M; t += TPB) {
            uint32_t k = keys[t];
            if (k && (k >> 24) == b3) atomicAdd(&hist2[(k >> 16) & 255u], 1u);
        }
        __syncthreads();
        suffix_scan_256(hist2);
        if (threadIdx.x < 256) {
            uint32_t si = hist2[threadIdx.x];
            uint32_t sn = (threadIdx.x < 255) ? hist2[threadIdx.x + 1] : 0u;
            if (si >= k2 && sn < k2) s_bin2 = threadIdx.x;
        }
        __syncthreads();
        T16 = (b3 << 8) | s_bin2;
    }

    // Compact finalists into pre-zeroed outb; exact np p computed only here.
    for (int t = threadIdx.x; t < M; t += TPB) {
        uint32_t k = keys[t];
        bool take = (k != 0) && ((k >> 16) >= T16);
        int pos = agg_push(&s_out, take);
        if (take && pos < 256) {
            int sIdx = t / KSLOT;                      // compile-time divisor
            int lr = (k >> 9) & 15, c = k & 511;       // lr: 4 bits (SR=16)
            int gidx = (sIdx * SR + lr) * W + c;
            float D = __fsub_rn(x1[gidx], x0[gidx]);
            float p = G_exact(D);
            outb[pos] = ((uint64_t)__float_as_uint(p) << 32) | (uint32_t)(~gidx);
        }
    }
    __syncthreads();

    // Rank-by-counting over unique u64 keys (2 barriers vs bitonic's 36).
    {
        int i = threadIdx.x & 255;
        int half = threadIdx.x >> 8;
        uint64_t ki = outb[i];
        uint32_t cnt = 0;
        int j0 = half * 128;
        #pragma unroll 4
        for (int j = j0; j < j0 + 128; ++j) cnt += (outb[j] > ki) ? 1u : 0u;
        atomicAdd(&rnk[i], cnt);
    }
    __syncthreads();

    // Decode: finalist with rank r < KTOP writes output row r directly.
    if (threadIdx.x < 256) {
        uint64_t k = outb[threadIdx.x];
        uint32_t r = rnk[threadIdx.x];
        if (k != 0 && r < KTOP) {
            int id = (int)(~(uint32_t)k);
            float val = __uint_as_float((uint32_t)(k >> 32));
            int yy = id / W, xx = id - yy * W;             // compile-time divisor
            constexpr float ds = BALL ? 4.0f : 16.0f;
            float xc = (float)xx * ds + (ds - 1.0f) * 0.5f;
            float yc = (float)yy * ds + (ds - 1.0f) * 0.5f;
            float t0 = 0.f, t1 = 0.f;
            float t2 = BALL ? 40.0f : 0.0f, t3 = BALL ? 40.0f : 0.0f;
            if (!BALL) {
                const float* bb = pbbox + (size_t)b * 4 * H * W;
                constexpr float sx = (float)W * ds, sy = (float)H * ds;
                t0 = bb[id]             * sx;
                t1 = bb[id + H * W]     * sy;
                t2 = bb[id + 2 * H * W] * sx;
                t3 = bb[id + 3 * H * W] * sy;
            }
            float bx = xc + t0, by = yc + t1;
            float* op = outp + (size_t)r * 5;
            op[0] = bx - 0.5f * t2;
            op[1] = by - 0.5f * t3;
            op[2] = bx + 0.5f * t2;
            op[3] = by + 0.5f * t3;
            op[4] = val;
        }
    }
}

__global__ __launch_bounds__(TPB) void stage2(const float* __restrict__ bmap,
                                              const float* __restrict__ pmap,
                                              const float* __restrict__ pbbox,
                                              const uint32_t* __restrict__ bkey,
                                              const uint32_t* __restrict__ pkey,
                                              float* __restrict__ out)
{
    extern __shared__ unsigned char smem[];
    if (blockIdx.x < NB) {
        int b = blockIdx.x;
        stage2_impl<HB, WB, NSB, true>(bmap, nullptr, bkey,
            out + (size_t)NB * KTOP * 5 + (size_t)b * KTOP * 5, b, smem);
    } else {
        int b = blockIdx.x - NB;
        stage2_impl<HP, WP, NSP, false>(pmap, pbbox, pkey,
            out + (size_t)b * KTOP * 5, b, smem);
    }
}

// ---- launch -----------------------------------------------------------------
extern "C" void kernel_launch(void* const* d_in, const int* in_sizes, int n_in,
                              void* d_out, int out_size, void* d_ws, size_t ws_size,
                              hipStream_t stream) {
    const float* pmap  = (const float*)d_in[0];   // [64,2,68,120]
    const float* pbbox = (const float*)d_in[1];   // [64,4,68,120]
    const float* bmap  = (const float*)d_in[2];   // [64,2,272,480]
    float* out = (float*)d_out;                   // player [64,100,5] then ball

    uint32_t* ws_bkey = (uint32_t*)d_ws;                       // 64*17*256 u32
    uint32_t* ws_pkey = ws_bkey + (size_t)NB * NSB * KSLOT;    // 64*5*256 u32
    // total ws: 1,441,792 B (within proven budget)

    // LDS: df 18*480*4=34560 + surv 6144 + hist 1024 + hist2 1024 = 42752 B
    //   -> 3 blk/CU (LDS-limited); grid 22x64=1408 blocks -> 1.83 rounds
    size_t lds1 = (size_t)(SR + 2) * WB * 4 + (size_t)CAP * 4 + 2048;
    stage1<<<dim3(NSB + NSP, NB), TPB, lds1, stream>>>(bmap, pmap, ws_bkey, ws_pkey);

    // LDS: keys 17*256*4=17408 + hist 1024 + hist2 1024 + rnk 1024 + outb 2048
    //    = 22528 B
    size_t lds2 = (size_t)NSB * KSLOT * 4 + 3072 + 2048;
    stage2<<<2 * NB, TPB, lds2, stream>>>(bmap, pmap, pbbox, ws_bkey, ws_pkey, out);
}

// Round 14
// 123.590 us; speedup vs baseline: 1.0971x; 1.0111x over previous
//
#include <hip/hip_runtime.h>
#include <stdint.h>
#include <math.h>

#define TPB   512    // 8 waves/block
#define KTOP  100
#define K1    128    // selection rank cut (per-slice in s1, per-image in s2)
#define KSLOT 256    // per-slice emitted u32 slots (K1 + fat tie-bin margin)
#define CAP   1536   // stage-1 survivor capacity (~855 expected/slice, +24 sigma)
#define SR    16     // slice rows

#define HB 272
#define WB 480
#define NSB 17       // 272/16
#define HP 68
#define WP 120
#define NSP 5        // ceil(68/16), last slice 4 rows
#define NB 64

// ============================================================================
// Validated invariants (prior session + this session, absmax 0.0):
//  - np-f32 softmax p is a MONOTONE function G of D = fl32(x1-x0);
//    G collapse window: for mx>0, ~6e-8*e^mx; for mx<=0, bounded by ~1e-6.
//  - NMS: keep iff p >= all 8 neighbors; D-space fast path + exact G on ties.
//  - top-k tie order: (p desc, idx asc)  ==  u64 key (p_bits<<32 | ~idx) desc.
//  - per-slice D16 rank-128 cut contains the slice's exact top-100.
// Ladder: R8 139.4 -> R14 128.1 (scaled tie certificate: distinct if
//  mx-v >= 4e-6*e^max(mx,0); f64 G_exact ~30 calls/run in stage1) ->
//  R15 126.3 (col-max, direct emit, stage2 batched load) -> R16/R18 125.0
//  (SR=16; reproduced). R17 (serial scan_pick) regressed -> reverted.
// R19: stage1 precomputes p for emitted survivors (D read from the live df
//  LDS tile -- bit-identical to stage2's recompute) into a parallel f32
//  workspace array. Stage2's compact loses its scattered map-gather AND all
//  f64 exp: p comes from LDS (loaded in the same batched pass as keys).
//  Stage2 now contains no f64 and no feature-map access.
// Structural hypotheses measured & rejected for stage1: R6/R7/R9/R10/R13/
//  R16(neutral)/R17. Remaining stage1 time is latency-structural.
// ============================================================================
__device__ __forceinline__ float G_exact(float D) {
    float t = -fabsf(D);
    float etf = (float)exp((double)t);       // correctly-rounded f32 exp
    return (D > 0.0f) ? __fdiv_rn(1.0f, __fadd_rn(etf, 1.0f))
                      : __fdiv_rn(etf, __fadd_rn(1.0f, etf));
}

__device__ __forceinline__ uint32_t flip_f32(float D) {
    uint32_t u = __float_as_uint(D);
    return (u & 0x80000000u) ? ~u : (u | 0x80000000u);
}

// Wave-aggregated counter push (stage2 only: low-frequency call sites).
__device__ __forceinline__ int agg_push(int* ctr, bool active) {
    uint64_t m = __ballot(active);
    int pos = -1;
    if (active) {
        int lane = threadIdx.x & 63;
        int lead = __ffsll((unsigned long long)m) - 1;
        int before = (int)__popcll(m & ((1ull << lane) - 1ull));
        int base = 0;
        if (lane == lead) base = atomicAdd(ctr, (int)__popcll(m));
        base = __shfl(base, lead, 64);
        pos = base + before;
    }
    return pos;
}

// Clustered histogram add (stage2 load pass only): one atomicAdd per
// DISTINCT bin per wave.
__device__ __forceinline__ void hist_clustered(uint32_t* hist, uint32_t bin, bool active) {
    uint64_t todo = __ballot(active);
    while (todo) {
        int lead = __ffsll((unsigned long long)todo) - 1;
        uint32_t b = (uint32_t)__shfl((int)bin, lead, 64);
        uint64_t same = __ballot(active && (bin == b));
        if ((int)(threadIdx.x & 63) == lead) atomicAdd(&hist[b], (uint32_t)__popcll(same));
        todo &= ~same;
    }
}

// In-place suffix-sum of 256 u32 bins: hist[i] <- sum_{j>=i} hist[j].
// Wave 0 via shuffles; ends with a barrier. (validated)
__device__ __forceinline__ void suffix_scan_256(uint32_t* hist) {
    if (threadIdx.x < 64) {
        int lane = threadIdx.x;
        uint32_t h0 = hist[4*lane+0], h1 = hist[4*lane+1];
        uint32_t h2 = hist[4*lane+2], h3 = hist[4*lane+3];
        uint32_t tot = h0 + h1 + h2 + h3;
        uint32_t run = tot;
        #pragma unroll
        for (int d = 1; d < 64; d <<= 1) {
            uint32_t o = __shfl_down(run, d, 64);
            if (lane + d < 64) run += o;
        }
        uint32_t ab = run - tot;
        hist[4*lane+3] = ab + h3;
        hist[4*lane+2] = ab + h3 + h2;
        hist[4*lane+1] = ab + h3 + h2 + h1;
        hist[4*lane+0] = ab + tot;
    }
    __syncthreads();
}

// 6-wide row window [c4-1 .. c4+4] from the LDS D-tile (OOB -> -inf).
template<int W>
__device__ __forceinline__ void row6(const float* df, int row, int c4, float* a) {
    const float4 m = ((const float4*)df)[(row * W + c4) >> 2];
    a[1] = m.x; a[2] = m.y; a[3] = m.z; a[4] = m.w;
    a[0] = (c4 > 0)     ? df[row * W + c4 - 1] : -INFINITY;
    a[5] = (c4 + 4 < W) ? df[row * W + c4 + 4] : -INFINITY;
}

// ---- stage 1 body: NMS + D16 radix-select, emit u32 keys + f32 p -----------
template<int H, int W, int NS>
__device__ __forceinline__ void stage1_impl(const float* __restrict__ x,
                                            int s, int b,
                                            uint32_t* __restrict__ key_out,
                                            float* __restrict__ p_out,
                                            unsigned char* smem)
{
    constexpr int W4 = W / 4;
    constexpr int tileRows = SR + 2;
    const int r0 = s * SR;
    const int rows = (H - r0 < SR) ? (H - r0) : SR;

    float*    df    = (float*)smem;                        // tileRows * W
    uint32_t* surv  = (uint32_t*)(df + tileRows * W);      // CAP
    uint32_t* hist  = surv + CAP;                          // 256
    uint32_t* hist2 = hist + 256;                          // 256 (level-2)
    __shared__ int s_cnt, s_out;
    __shared__ uint32_t s_bin, s_ab, s_bin2, s_none;
    if (threadIdx.x == 0) { s_cnt = 0; s_out = 0; s_none = 0; }
    if (threadIdx.x < 256) { hist[threadIdx.x] = 0; hist2[threadIdx.x] = 0; }

    // Direct-global emit: zero this slice's KSLOT key slots now (overlaps
    // tile load); compact overwrites [0, s_out) later. p slots need no
    // zeroing: stage2 reads p only where key != 0.
    uint32_t* ko = key_out + ((size_t)b * NS + s) * KSLOT;
    float*    kp = p_out   + ((size_t)b * NS + s) * KSLOT;
    if (threadIdx.x < KSLOT) ko[threadIdx.x] = 0u;

    const float*  x0  = x + (size_t)b * 2 * H * W;
    const float*  x1  = x0 + (size_t)H * W;
    const float4* x0v = (const float4*)x0;
    const float4* x1v = (const float4*)x1;
    float4* dfv = (float4*)df;

    // D tile (rows r0-1 .. r0+SR), float4-vectorized; OOB rows -> -inf.
    constexpr int nt4 = tileRows * W4;
    for (int t = threadIdx.x; t < nt4; t += TPB) {
        int tr = t / W4, c4 = t - tr * W4;        // compile-time divisor
        int r = r0 - 1 + tr;
        float4 d4 = make_float4(-INFINITY, -INFINITY, -INFINITY, -INFINITY);
        if (r >= 0 && r < H) {
            float4 a = x0v[r * W4 + c4];
            float4 c = x1v[r * W4 + c4];
            d4.x = __fsub_rn(c.x, a.x);
            d4.y = __fsub_rn(c.y, a.y);
            d4.z = __fsub_rn(c.z, a.z);
            d4.w = __fsub_rn(c.w, a.w);
        }
        dfv[t] = d4;
    }
    __syncthreads();

    // NMS (4 cells/iter) + level-1 histogram fused into the keep path.
    // Column-max sharing (bit-identical 8-neighbor max); R14 scaled tie
    // certificate -> f64 G_exact fires ~30x per RUN here.
    const int groups = rows * W4;
    for (int g = threadIdx.x; g < groups; g += TPB) {
        int lr = g / W4, c4 = (g - lr * W4) << 2; // compile-time divisor
        int tr = lr + 1;
        float ap[6], ac[6], an[6], vx[6];
        row6<W>(df, tr - 1, c4, ap);
        row6<W>(df, tr,     c4, ac);
        row6<W>(df, tr + 1, c4, an);
        #pragma unroll
        for (int i = 0; i < 6; ++i) vx[i] = fmaxf(fmaxf(ap[i], an[i]), ac[i]);
        #pragma unroll
        for (int j = 0; j < 4; ++j) {
            float v = ac[j + 1];
            float mx = fmaxf(fmaxf(fmaxf(vx[j], vx[j+2]), ap[j+1]), an[j+1]);
            float thr = 4e-6f * __expf(fmaxf(mx, 0.0f)); // >=16x/4x margin certificate
            bool keep;
            if (v >= mx) keep = true;                    // exact
            else if (mx - v >= thr) keep = false;        // certified G-distinct
            else keep = (G_exact(v) == G_exact(mx));     // ultra-rare exact tie check
            if (keep) {
                uint32_t key16 = flip_f32(v) >> 16;
                int pos = atomicAdd(&s_cnt, 1);
                if (pos < CAP)
                    surv[pos] = (key16 << 16) | ((uint32_t)lr << 9) | (uint32_t)(c4 + j);
                atomicAdd(&hist[key16 >> 8], 1u);
            }
        }
    }
    __syncthreads();
    const int n = (s_cnt < CAP) ? s_cnt : CAP;

    // Level-1 select on D16 high byte.
    suffix_scan_256(hist);
    if (threadIdx.x < 256) {
        uint32_t si = hist[threadIdx.x];
        uint32_t sn = (threadIdx.x < 255) ? hist[threadIdx.x + 1] : 0u;
        if (threadIdx.x == 0 && si < K1) s_none = 1;
        if (si >= K1 && sn < K1) { s_bin = threadIdx.x; s_ab = sn; }
    }
    __syncthreads();

    uint32_t T16 = 0;
    if (!s_none) {
        const uint32_t b3 = s_bin;
        const uint32_t k2 = K1 - s_ab;
        // Level-2: hist2 pre-zeroed in the init phase (no rezero barrier).
        for (int t = threadIdx.x; t < n; t += TPB) {
            uint32_t sv = surv[t];
            if ((sv >> 24) == b3) atomicAdd(&hist2[(sv >> 16) & 255u], 1u);
        }
        __syncthreads();
        suffix_scan_256(hist2);
        if (threadIdx.x < 256) {
            uint32_t si = hist2[threadIdx.x];
            uint32_t sn = (threadIdx.x < 255) ? hist2[threadIdx.x + 1] : 0u;
            if (si >= k2 && sn < k2) s_bin2 = threadIdx.x;
        }
        __syncthreads();
        T16 = (b3 << 8) | s_bin2;
    }

    // Compact survivors with D16 >= T16: scatter key + exact p to global.
    // D re-read from the live df tile (bit-identical to the map recompute);
    // ~n/TPB masked G_exact calls per thread -- dense, no amplification.
    for (int t = threadIdx.x; t < n; t += TPB) {
        uint32_t sv = surv[t];
        if ((sv >> 16) >= T16) {
            int pos = atomicAdd(&s_out, 1);
            if (pos < KSLOT) {
                int lr = (sv >> 9) & 15, c = sv & 511;
                float D = df[(lr + 1) * W + c];
                ko[pos] = sv;
                kp[pos] = G_exact(D);
            }
        }
    }
}

__global__ __launch_bounds__(TPB) void stage1(const float* __restrict__ bmap,
                                              const float* __restrict__ pmap,
                                              uint32_t* __restrict__ bkey,
                                              uint32_t* __restrict__ pkey,
                                              float* __restrict__ bp,
                                              float* __restrict__ pp)
{
    extern __shared__ unsigned char smem[];
    if (blockIdx.x < NSB)
        stage1_impl<HB, WB, NSB>(bmap, blockIdx.x, blockIdx.y, bkey, bp, smem);
    else
        stage1_impl<HP, WP, NSP>(pmap, blockIdx.x - NSB, blockIdx.y, pkey, pp, smem);
}

// ---- stage 2 body: D16 select -> p re-rank of <=256 -> decode --------------
// No f64, no feature-map access: p arrives precomputed from stage1.
template<int H, int W, int NS, bool BALL>
__device__ __forceinline__ void stage2_impl(const float* __restrict__ pbbox,
                                            const uint32_t* __restrict__ key_in,
                                            const float* __restrict__ p_in,
                                            float* __restrict__ outp,
                                            int b, unsigned char* smem)
{
    constexpr int M = NS * KSLOT;
    const uint32_t* kin = key_in + (size_t)b * M;
    const float*    pin = p_in   + (size_t)b * M;

    uint32_t* keys  = (uint32_t*)smem;           // M
    float*    pvals = (float*)(keys + M);        // M
    uint32_t* hist  = (uint32_t*)(pvals + M);    // 256 (level-1)
    uint32_t* hist2 = hist + 256;                // 256 (level-2)
    uint32_t* rnk   = hist2 + 256;               // 256 (ranks)
    uint64_t* outb  = (uint64_t*)(rnk + 256);    // 256
    __shared__ int s_out;
    __shared__ uint32_t s_bin, s_ab, s_bin2, s_none;
    if (threadIdx.x == 0) { s_out = 0; s_none = 0; }
    if (threadIdx.x < 256) {
        hist[threadIdx.x] = 0; hist2[threadIdx.x] = 0;
        rnk[threadIdx.x] = 0; outb[threadIdx.x] = 0;
    }
    // Defensive zero of the 100 output rows (rank-scatter fills real rows).
    for (int t = threadIdx.x; t < KTOP * 5; t += TPB) outp[t] = 0.f;
    __syncthreads();

    // Batched load: issue ALL key+p global loads into registers before any
    // use (sched_barrier(0) pins issue order -- 1 blk/CU has nothing else
    // to hide the round-trips behind). Then LDS store + hist.
    {
        constexpr int NLD = (M + TPB - 1) / TPB;
        uint32_t kr[NLD];
        float    pr[NLD];
        #pragma unroll
        for (int u = 0; u < NLD; ++u) {
            int t = threadIdx.x + u * TPB;
            kr[u] = (t < M) ? kin[t] : 0u;
            pr[u] = (t < M) ? pin[t] : 0.f;
        }
        __builtin_amdgcn_sched_barrier(0);
        #pragma unroll
        for (int u = 0; u < NLD; ++u) {
            int t = threadIdx.x + u * TPB;
            if (t < M) { keys[t] = kr[u]; pvals[t] = pr[u]; }
            hist_clustered(hist, kr[u] >> 24, (t < M) && (kr[u] != 0u));
        }
    }
    __syncthreads();
    suffix_scan_256(hist);
    if (threadIdx.x < 256) {
        uint32_t si = hist[threadIdx.x];
        uint32_t sn = (threadIdx.x < 255) ? hist[threadIdx.x + 1] : 0u;
        if (threadIdx.x == 0 && si < K1) s_none = 1;
        if (si >= K1 && sn < K1) { s_bin = threadIdx.x; s_ab = sn; }
    }
    __syncthreads();

    uint32_t T16 = 0;
    if (!s_none) {
        const uint32_t b3 = s_bin;
        const uint32_t k2 = K1 - s_ab;
        // Level-2: hist2 pre-zeroed in the init phase.
        for (int t = threadIdx.x; t < M; t += TPB) {
            uint32_t k = keys[t];
            if (k && (k >> 24) == b3) atomicAdd(&hist2[(k >> 16) & 255u], 1u);
        }
        __syncthreads();
        suffix_scan_256(hist2);
        if (threadIdx.x < 256) {
            uint32_t si = hist2[threadIdx.x];
            uint32_t sn = (threadIdx.x < 255) ? hist2[threadIdx.x + 1] : 0u;
            if (si >= k2 && sn < k2) s_bin2 = threadIdx.x;
        }
        __syncthreads();
        T16 = (b3 << 8) | s_bin2;
    }

    // Compact finalists into pre-zeroed outb; p comes from LDS (no gather,
    // no f64). gidx reconstructed from the key exactly as before.
    for (int t = threadIdx.x; t < M; t += TPB) {
        uint32_t k = keys[t];
        bool take = (k != 0) && ((k >> 16) >= T16);
        int pos = agg_push(&s_out, take);
        if (take && pos < 256) {
            int sIdx = t / KSLOT;                      // compile-time divisor
            int lr = (k >> 9) & 15, c = k & 511;       // lr: 4 bits (SR=16)
            int gidx = (sIdx * SR + lr) * W + c;
            float p = pvals[t];
            outb[pos] = ((uint64_t)__float_as_uint(p) << 32) | (uint32_t)(~gidx);
        }
    }
    __syncthreads();

    // Rank-by-counting over unique u64 keys (2 barriers vs bitonic's 36).
    {
        int i = threadIdx.x & 255;
        int half = threadIdx.x >> 8;
        uint64_t ki = outb[i];
        uint32_t cnt = 0;
        int j0 = half * 128;
        #pragma unroll 4
        for (int j = j0; j < j0 + 128; ++j) cnt += (outb[j] > ki) ? 1u : 0u;
        atomicAdd(&rnk[i], cnt);
    }
    __syncthreads();

    // Decode: finalist with rank r < KTOP writes output row r directly.
    if (threadIdx.x < 256) {
        uint64_t k = outb[threadIdx.x];
        uint32_t r = rnk[threadIdx.x];
        if (k != 0 && r < KTOP) {
            int id = (int)(~(uint32_t)k);
            float val = __uint_as_float((uint32_t)(k >> 32));
            int yy = id / W, xx = id - yy * W;             // compile-time divisor
            constexpr float ds = BALL ? 4.0f : 16.0f;
            float xc = (float)xx * ds + (ds - 1.0f) * 0.5f;
            float yc = (float)yy * ds + (ds - 1.0f) * 0.5f;
            float t0 = 0.f, t1 = 0.f;
            float t2 = BALL ? 40.0f : 0.0f, t3 = BALL ? 40.0f : 0.0f;
            if (!BALL) {
                const float* bb = pbbox + (size_t)b * 4 * H * W;
                constexpr float sx = (float)W * ds, sy = (float)H * ds;
                t0 = bb[id]             * sx;
                t1 = bb[id + H * W]     * sy;
                t2 = bb[id + 2 * H * W] * sx;
                t3 = bb[id + 3 * H * W] * sy;
            }
            float bx = xc + t0, by = yc + t1;
            float* op = outp + (size_t)r * 5;
            op[0] = bx - 0.5f * t2;
            op[1] = by - 0.5f * t3;
            op[2] = bx + 0.5f * t2;
            op[3] = by + 0.5f * t3;
            op[4] = val;
        }
    }
}

__global__ __launch_bounds__(TPB) void stage2(const float* __restrict__ pbbox,
                                              const uint32_t* __restrict__ bkey,
                                              const uint32_t* __restrict__ pkey,
                                              const float* __restrict__ bp,
                                              const float* __restrict__ pp,
                                              float* __restrict__ out)
{
    extern __shared__ unsigned char smem[];
    if (blockIdx.x < NB) {
        int b = blockIdx.x;
        stage2_impl<HB, WB, NSB, true>(nullptr, bkey, bp,
            out + (size_t)NB * KTOP * 5 + (size_t)b * KTOP * 5, b, smem);
    } else {
        int b = blockIdx.x - NB;
        stage2_impl<HP, WP, NSP, false>(pbbox, pkey, pp,
            out + (size_t)b * KTOP * 5, b, smem);
    }
}

// ---- launch -----------------------------------------------------------------
extern "C" void kernel_launch(void* const* d_in, const int* in_sizes, int n_in,
                              void* d_out, int out_size, void* d_ws, size_t ws_size,
                              hipStream_t stream) {
    const float* pmap  = (const float*)d_in[0];   // [64,2,68,120]
    const float* pbbox = (const float*)d_in[1];   // [64,4,68,120]
    const float* bmap  = (const float*)d_in[2];   // [64,2,272,480]
    float* out = (float*)d_out;                   // player [64,100,5] then ball

    uint32_t* ws_bkey = (uint32_t*)d_ws;                       // 64*17*256 u32
    uint32_t* ws_pkey = ws_bkey + (size_t)NB * NSB * KSLOT;    // 64*5*256 u32
    float*    ws_bp   = (float*)(ws_pkey + (size_t)NB * NSP * KSLOT); // 64*17*256 f32
    float*    ws_pp   = ws_bp + (size_t)NB * NSB * KSLOT;             // 64*5*256 f32
    // total ws: 2,883,584 B (within proven budget)

    // LDS: df 18*480*4=34560 + surv 6144 + hist 1024 + hist2 1024 = 42752 B
    //   -> 3 blk/CU (LDS-limited); grid 22x64=1408 blocks -> 1.83 rounds
    size_t lds1 = (size_t)(SR + 2) * WB * 4 + (size_t)CAP * 4 + 2048;
    stage1<<<dim3(NSB + NSP, NB), TPB, lds1, stream>>>(bmap, pmap,
                                                       ws_bkey, ws_pkey, ws_bp, ws_pp);

    // LDS: keys 17408 + pvals 17408 + hist 1024 + hist2 1024 + rnk 1024
    //    + outb 2048 = 39936 B
    size_t lds2 = (size_t)NSB * KSLOT * 8 + 5120;
    stage2<<<2 * NB, TPB, lds2, stream>>>(pbbox, ws_bkey, ws_pkey, ws_bp, ws_pp, out);
}